// Round 5
// baseline (151.097 us; speedup 1.0000x reference)
//
#include <hip/hip_runtime.h>
#include <hip/hip_bf16.h>
#include <math.h>

#define NH 12
#define DH 64
#define BB 2
#define NN 2048
#define DM 768

typedef short v8s __attribute__((ext_vector_type(8)));
typedef float v4f __attribute__((ext_vector_type(4)));
typedef float v16f __attribute__((ext_vector_type(16)));

__device__ __forceinline__ unsigned short f2bf(float f) {
    union { float f; unsigned u; } x; x.f = f;
    unsigned r = x.u + 0x7fffu + ((x.u >> 16) & 1u);
    return (unsigned short)(r >> 16);
}

__device__ __forceinline__ int cvtpk(float lo, float hi2) {
    int r;
    asm("v_cvt_pk_bf16_f32 %0, %1, %2" : "=v"(r) : "v"(lo), "v"(hi2));
    return r;
}

__device__ __forceinline__ void glds16(const void* g, void* l) {
    __builtin_amdgcn_global_load_lds((const __attribute__((address_space(1))) void*)g,
                                     (__attribute__((address_space(3))) void*)l, 16, 0, 0);
}

// ---- cast x (fp32 -> bf16, layout-preserving) ----
__global__ __launch_bounds__(256) void cast_x_k(const float* __restrict__ in,
                                                unsigned short* __restrict__ out, int n) {
    int i = (blockIdx.x * 256 + threadIdx.x) * 4;
    if (i >= n) return;
    float4 v = *(const float4*)(in + i);
    ushort4 o;
    o.x = f2bf(v.x); o.y = f2bf(v.y); o.z = f2bf(v.z); o.w = f2bf(v.w);
    *(ushort4*)(out + i) = o;
}

// ---- cast + transpose weights via LDS tile (64x64): out[c][k] = in[k][c] ----
__global__ __launch_bounds__(256) void cast_wT_k(const float* __restrict__ w0, const float* __restrict__ w1,
                                                 const float* __restrict__ w2, const float* __restrict__ w3,
                                                 unsigned short* __restrict__ o0, unsigned short* __restrict__ o1,
                                                 unsigned short* __restrict__ o2, unsigned short* __restrict__ o3) {
    __shared__ unsigned short t[64][65];
    const float* in; unsigned short* out;
    switch (blockIdx.y) {
        case 0: in = w0; out = o0; break;
        case 1: in = w1; out = o1; break;
        case 2: in = w2; out = o2; break;
        default: in = w3; out = o3; break;
    }
    int kt = blockIdx.x / 12, ct = blockIdx.x % 12;
    int rr = threadIdx.x >> 4, cc = threadIdx.x & 15;
#pragma unroll
    for (int it = 0; it < 4; it++) {
        int row = kt * 64 + it * 16 + rr;
        int col = ct * 64 + cc * 4;
        float4 v = *(const float4*)(in + row * 768 + col);
        t[it * 16 + rr][cc * 4 + 0] = f2bf(v.x);
        t[it * 16 + rr][cc * 4 + 1] = f2bf(v.y);
        t[it * 16 + rr][cc * 4 + 2] = f2bf(v.z);
        t[it * 16 + rr][cc * 4 + 3] = f2bf(v.w);
    }
    __syncthreads();
#pragma unroll
    for (int it = 0; it < 4; it++) {
        int c_l = it * 16 + rr;
        int k_l = cc * 4;
        ushort4 o;
        o.x = t[k_l + 0][c_l];
        o.y = t[k_l + 1][c_l];
        o.z = t[k_l + 2][c_l];
        o.w = t[k_l + 3][c_l];
        *(ushort4*)(out + (ct * 64 + c_l) * 768 + kt * 64 + k_l) = o;
    }
}

// ---- fused QKV projection as one GEMM over N=2304 (concat wq|wk|wv cols) ----
__global__ __launch_bounds__(256) void qkv_gemm_k(
    const unsigned short* __restrict__ xb,
    const unsigned short* __restrict__ wqT, const unsigned short* __restrict__ wkT,
    const unsigned short* __restrict__ wvT,
    const float* __restrict__ bq, const float* __restrict__ bk, const float* __restrict__ bv,
    unsigned short* __restrict__ q, unsigned short* __restrict__ k, unsigned short* __restrict__ vT) {
    __shared__ unsigned short Abuf[2][128 * 32];
    __shared__ unsigned short Bbuf[2][128 * 32];

    int ctile = blockIdx.x;
    int mtile = blockIdx.y;
    int mat = ctile / 6;
    int col0 = (ctile % 6) * 128;
    const unsigned short* Bsrc = (mat == 0) ? wqT : ((mat == 1) ? wkT : wvT);
    const float* bias = (mat == 0) ? bq : ((mat == 1) ? bk : bv);

    int tid = threadIdx.x;
    int w = tid >> 6, l = tid & 63;
    int q16 = l & 15, g = l >> 4;
    int wr = w >> 1, wc = w & 1;

    int srow0 = tid >> 2;
    int ss = tid & 3;

    auto stage = [&](int tt, int buf) {
        int k0 = tt * 32;
#pragma unroll
        for (int i = 0; i < 2; ++i) {
            int row = srow0 + i * 64;
            int c16 = ss ^ ((row >> 1) & 3);
            glds16(xb + (mtile * 128 + row) * 768 + k0 + (c16 << 3),
                   (char*)&Abuf[buf][0] + i * 4096 + tid * 16);
            glds16(Bsrc + (col0 + row) * 768 + k0 + (c16 << 3),
                   (char*)&Bbuf[buf][0] + i * 4096 + tid * 16);
        }
    };

    v4f zero = {0.f, 0.f, 0.f, 0.f};
    v4f acc[4][4];
#pragma unroll
    for (int i = 0; i < 4; i++)
#pragma unroll
        for (int j = 0; j < 4; j++) acc[i][j] = zero;

    stage(0, 0);
    __syncthreads();

    for (int tt = 0; tt < 24; ++tt) {
        int cur = tt & 1;
        if (tt + 1 < 24) stage(tt + 1, cur ^ 1);
        const char* Ab = (const char*)&Abuf[cur][0];
        const char* Bb = (const char*)&Bbuf[cur][0];
        v8s af[4], bf[4];
#pragma unroll
        for (int f = 0; f < 4; f++) {
            int arow = wr * 64 + f * 16 + q16;
            af[f] = *(const v8s*)(Ab + arow * 64 + ((g ^ ((arow >> 1) & 3)) << 4));
            int brow = wc * 64 + f * 16 + q16;
            bf[f] = *(const v8s*)(Bb + brow * 64 + ((g ^ ((brow >> 1) & 3)) << 4));
        }
#pragma unroll
        for (int i = 0; i < 4; i++)
#pragma unroll
            for (int j = 0; j < 4; j++)
                acc[i][j] = __builtin_amdgcn_mfma_f32_16x16x32_bf16(af[i], bf[j], acc[i][j], 0, 0, 0);
        __syncthreads();
    }

    const float QSCL = 0.125f * 1.44269504088896340736f;
#pragma unroll
    for (int i = 0; i < 4; i++)
#pragma unroll
        for (int j = 0; j < 4; j++)
#pragma unroll
            for (int r = 0; r < 4; r++) {
                int gr = mtile * 128 + wr * 64 + i * 16 + 4 * g + r;
                int gcl = col0 + wc * 64 + j * 16 + q16;
                int b = gr / NN, n = gr % NN;
                int h = gcl / DH, d = gcl % DH;
                int bh = b * NH + h;
                float v = acc[i][j][r] + bias[gcl];
                if (mat == 0)      q[(bh * NN + n) * DH + d]  = f2bf(v * QSCL);
                else if (mat == 1) k[(bh * NN + n) * DH + d]  = f2bf(v);
                else               vT[(bh * DH + d) * NN + n] = f2bf(v);
            }
}

// ---- flash attention, 32x32 MFMA: 2 waves x 32 q-rows, kv tile 64, LDS-staged K/V ----
// QK^T swapped: S^T = mfma(K, Q); P redistributed in-register (cvt_pk + shfl_xor 32);
// PV: O = mfma(P, V). Defer-max rescale (THR=8) via ds_bpermute.
#define MKFRAG(PC, BASE, FR) {                                                     \
    int a0 = cvtpk(PC[BASE + 0], PC[BASE + 1]), a1 = cvtpk(PC[BASE + 2], PC[BASE + 3]); \
    int b0 = cvtpk(PC[BASE + 4], PC[BASE + 5]), b1 = cvtpk(PC[BASE + 6], PC[BASE + 7]); \
    int t0 = hi ? a0 : b0, t1 = hi ? a1 : b1;                                      \
    int r0 = __shfl_xor(t0, 32), r1 = __shfl_xor(t1, 32);                          \
    union { int i[4]; v8s s; } u_;                                                 \
    u_.i[0] = hi ? r0 : a0; u_.i[1] = hi ? r1 : a1;                                \
    u_.i[2] = hi ? b0 : r0; u_.i[3] = hi ? b1 : r1;                                \
    FR = u_.s; }

__global__ __launch_bounds__(128) void attn_k(
    const unsigned short* __restrict__ q, const unsigned short* __restrict__ k,
    const unsigned short* __restrict__ vT, unsigned short* __restrict__ z) {
    __shared__ unsigned short Kb[2][4096];
    __shared__ unsigned short Vb[2][4096];

    int bh = blockIdx.x % 24;                 // 24≡0 mod 8 -> whole head on one XCD class
    int qt = blockIdx.x / 24;                 // 0..31
    int b = bh / NH, h = bh % NH;
    int tid = threadIdx.x;
    int w = tid >> 6, l = tid & 63;
    int hi = l >> 5, ln = l & 31, x7 = l & 7;
    const unsigned short* qp = q + (size_t)bh * NN * DH;
    const unsigned short* kp = k + (size_t)bh * NN * DH;
    const unsigned short* vp = vT + (size_t)bh * DH * NN;

    int qrow = qt * 64 + w * 32 + ln;
    v8s qf[4];
#pragma unroll
    for (int ks = 0; ks < 4; ++ks)
        qf[ks] = *(const v8s*)(qp + qrow * DH + 16 * ks + 8 * hi);

    auto stage = [&](int t, int buf) {
        int kv = t * 64;
#pragma unroll
        for (int i = 0; i < 4; ++i) {
            int slot = tid + 128 * i;
            int row = slot >> 3;
            int c16 = (slot & 7) ^ (row & 7);
            glds16(kp + (kv + row) * DH + (c16 << 3), (char*)&Kb[buf][0] + slot * 16);
            glds16(vp + row * NN + kv + (c16 << 3), (char*)&Vb[buf][0] + slot * 16);
        }
    };

    v16f o0, o1;
#pragma unroll
    for (int i = 0; i < 16; i++) { o0[i] = 0.f; o1[i] = 0.f; }
    float mrow = -INFINITY, lsum = 0.f;

    stage(0, 0);
    __syncthreads();

    for (int t = 0; t < NN / 64; ++t) {
        int cur = t & 1;
        if (t + 1 < NN / 64) stage(t + 1, cur ^ 1);
        const char* kbp = (const char*)&Kb[cur][0];
        const char* vbp = (const char*)&Vb[cur][0];

        v16f s0, s1;
#pragma unroll
        for (int i = 0; i < 16; i++) { s0[i] = 0.f; s1[i] = 0.f; }

        // ---- QK^T: S^T[64 kv][32 q] ----
        {
            v8s kf0[4], kf1[4];
#pragma unroll
            for (int ks = 0; ks < 4; ++ks) {
                kf0[ks] = *(const v8s*)(kbp + ln * 128 + (((2 * ks + hi) ^ x7) << 4));
                kf1[ks] = *(const v8s*)(kbp + (32 + ln) * 128 + (((2 * ks + hi) ^ x7) << 4));
            }
            __builtin_amdgcn_s_setprio(1);
#pragma unroll
            for (int ks = 0; ks < 4; ++ks) {
                s0 = __builtin_amdgcn_mfma_f32_32x32x16_bf16(kf0[ks], qf[ks], s0, 0, 0, 0);
                s1 = __builtin_amdgcn_mfma_f32_32x32x16_bf16(kf1[ks], qf[ks], s1, 0, 0, 0);
            }
            __builtin_amdgcn_s_setprio(0);
        }

        // ---- online softmax (defer-max, THR=8) ----
        float vmax = -1e30f;
#pragma unroll
        for (int i = 0; i < 16; i++) vmax = fmaxf(vmax, fmaxf(s0[i], s1[i]));
        vmax = fmaxf(vmax, __shfl_xor(vmax, 32));

        int need = !__all(vmax <= mrow + 8.f);
        if (need) {
            float mn = fmaxf(mrow, vmax);
            float sc = exp2f(mrow - mn);
#pragma unroll
            for (int r = 0; r < 16; ++r) {
                int addr = 4 * ((r & 3) + 8 * (r >> 2)) + (hi << 4);
                float scr = __uint_as_float(
                    __builtin_amdgcn_ds_bpermute(addr, __float_as_uint(sc)));
                o0[r] *= scr; o1[r] *= scr;
            }
            lsum *= sc;
            mrow = mn;
        }

        float rs = 0.f;
#pragma unroll
        for (int i = 0; i < 16; i++) {
            s0[i] = exp2f(s0[i] - mrow);
            s1[i] = exp2f(s1[i] - mrow);
            rs += s0[i] + s1[i];
        }
        rs += __shfl_xor(rs, 32);
        lsum += rs;

        // ---- P fragments (in-register redistribution) ----
        v8s pf[4];
        MKFRAG(s0, 0, pf[0]);
        MKFRAG(s0, 8, pf[1]);
        MKFRAG(s1, 0, pf[2]);
        MKFRAG(s1, 8, pf[3]);

        // ---- PV: O[32 q][64 d] ----
        {
            v8s vf0[4], vf1[4];
#pragma unroll
            for (int ks = 0; ks < 4; ++ks) {
                vf0[ks] = *(const v8s*)(vbp + ln * 128 + (((2 * ks + hi) ^ x7) << 4));
                vf1[ks] = *(const v8s*)(vbp + (32 + ln) * 128 + (((2 * ks + hi) ^ x7) << 4));
            }
            __builtin_amdgcn_s_setprio(1);
#pragma unroll
            for (int ks = 0; ks < 4; ++ks) {
                o0 = __builtin_amdgcn_mfma_f32_32x32x16_bf16(pf[ks], vf0[ks], o0, 0, 0, 0);
                o1 = __builtin_amdgcn_mfma_f32_32x32x16_bf16(pf[ks], vf1[ks], o1, 0, 0, 0);
            }
            __builtin_amdgcn_s_setprio(0);
        }
        __syncthreads();
    }

    float inv = 1.f / lsum;
#pragma unroll
    for (int r = 0; r < 16; ++r) {
        int addr = 4 * ((r & 3) + 8 * (r >> 2)) + (hi << 4);
        float ir = __uint_as_float(__builtin_amdgcn_ds_bpermute(addr, __float_as_uint(inv)));
        int qg = qt * 64 + w * 32 + (r & 3) + 8 * (r >> 2) + 4 * hi;
        size_t base = ((size_t)(b * NN + qg)) * DM + h * DH;
        z[base + ln]      = f2bf(o0[r] * ir);
        z[base + 32 + ln] = f2bf(o1[r] * ir);
    }
}

// ---- output projection: z[4096,768] @ wo + bo -> fp32; tiled ----
__global__ __launch_bounds__(256) void out_gemm_k(
    const unsigned short* __restrict__ zb, const unsigned short* __restrict__ woT,
    const float* __restrict__ bo, float* __restrict__ out) {
    __shared__ unsigned short Abuf[2][128 * 32];
    __shared__ unsigned short Bbuf[2][128 * 32];

    int ctile = blockIdx.x;
    int mtile = blockIdx.y;
    int col0 = ctile * 128;

    int tid = threadIdx.x;
    int w = tid >> 6, l = tid & 63;
    int q16 = l & 15, g = l >> 4;
    int wr = w >> 1, wc = w & 1;

    int srow0 = tid >> 2;
    int ss = tid & 3;

    auto stage = [&](int tt, int buf) {
        int k0 = tt * 32;
#pragma unroll
        for (int i = 0; i < 2; ++i) {
            int row = srow0 + i * 64;
            int c16 = ss ^ ((row >> 1) & 3);
            glds16(zb + (mtile * 128 + row) * 768 + k0 + (c16 << 3),
                   (char*)&Abuf[buf][0] + i * 4096 + tid * 16);
            glds16(woT + (col0 + row) * 768 + k0 + (c16 << 3),
                   (char*)&Bbuf[buf][0] + i * 4096 + tid * 16);
        }
    };

    v4f zero = {0.f, 0.f, 0.f, 0.f};
    v4f acc[4][4];
#pragma unroll
    for (int i = 0; i < 4; i++)
#pragma unroll
        for (int j = 0; j < 4; j++) acc[i][j] = zero;

    stage(0, 0);
    __syncthreads();

    for (int tt = 0; tt < 24; ++tt) {
        int cur = tt & 1;
        if (tt + 1 < 24) stage(tt + 1, cur ^ 1);
        const char* Ab = (const char*)&Abuf[cur][0];
        const char* Bb = (const char*)&Bbuf[cur][0];
        v8s af[4], bf[4];
#pragma unroll
        for (int f = 0; f < 4; f++) {
            int arow = wr * 64 + f * 16 + q16;
            af[f] = *(const v8s*)(Ab + arow * 64 + ((g ^ ((arow >> 1) & 3)) << 4));
            int brow = wc * 64 + f * 16 + q16;
            bf[f] = *(const v8s*)(Bb + brow * 64 + ((g ^ ((brow >> 1) & 3)) << 4));
        }
#pragma unroll
        for (int i = 0; i < 4; i++)
#pragma unroll
            for (int j = 0; j < 4; j++)
                acc[i][j] = __builtin_amdgcn_mfma_f32_16x16x32_bf16(af[i], bf[j], acc[i][j], 0, 0, 0);
        __syncthreads();
    }

#pragma unroll
    for (int i = 0; i < 4; i++)
#pragma unroll
        for (int j = 0; j < 4; j++)
#pragma unroll
            for (int r = 0; r < 4; r++) {
                int gr = mtile * 128 + wr * 64 + i * 16 + 4 * g + r;
                int gc = col0 + wc * 64 + j * 16 + q16;
                out[gr * 768 + gc] = acc[i][j][r] + bo[gc];
            }
}

extern "C" void kernel_launch(void* const* d_in, const int* in_sizes, int n_in,
                              void* d_out, int out_size, void* d_ws, size_t ws_size,
                              hipStream_t stream) {
    const float* x  = (const float*)d_in[0];
    const float* wq = (const float*)d_in[1];
    const float* bq = (const float*)d_in[2];
    const float* wk = (const float*)d_in[3];
    const float* bk = (const float*)d_in[4];
    const float* wv = (const float*)d_in[5];
    const float* bv = (const float*)d_in[6];
    const float* wo = (const float*)d_in[7];
    const float* bo = (const float*)d_in[8];
    float* out = (float*)d_out;

    const int NX = BB * NN * DM;
    const int NW = 768 * 768;

    unsigned short* wsp = (unsigned short*)d_ws;
    unsigned short* xb  = wsp;
    unsigned short* wqT = xb + NX;
    unsigned short* wkT = wqT + NW;
    unsigned short* wvT = wkT + NW;
    unsigned short* woT = wvT + NW;
    unsigned short* qb  = woT + NW;
    unsigned short* kb  = qb + NX;
    unsigned short* vTb = kb + NX;
    unsigned short* zb  = vTb + NX;

    cast_x_k<<<NX / (256 * 4), 256, 0, stream>>>(x, xb, NX);
    cast_wT_k<<<dim3(144, 4), 256, 0, stream>>>(wq, wk, wv, wo, wqT, wkT, wvT, woT);
    qkv_gemm_k<<<dim3(18, 32), 256, 0, stream>>>(xb, wqT, wkT, wvT, bq, bk, bv, qb, kb, vTb);
    attn_k<<<BB * NH * (NN / 64), 128, 0, stream>>>(qb, kb, vTb, zb);
    out_gemm_k<<<dim3(6, 32), 256, 0, stream>>>(zb, woT, bo, out);
}

// Round 6
// 147.645 us; speedup vs baseline: 1.0234x; 1.0234x over previous
//
#include <hip/hip_runtime.h>
#include <hip/hip_bf16.h>
#include <math.h>

#define NH 12
#define DH 64
#define BB 2
#define NN 2048
#define DM 768

typedef short v8s __attribute__((ext_vector_type(8)));
typedef float v4f __attribute__((ext_vector_type(4)));
typedef float v16f __attribute__((ext_vector_type(16)));

__device__ __forceinline__ unsigned short f2bf(float f) {
    union { float f; unsigned u; } x; x.f = f;
    unsigned r = x.u + 0x7fffu + ((x.u >> 16) & 1u);
    return (unsigned short)(r >> 16);
}

__device__ __forceinline__ int cvtpk(float lo, float hi2) {
    int r;
    asm("v_cvt_pk_bf16_f32 %0, %1, %2" : "=v"(r) : "v"(lo), "v"(hi2));
    return r;
}

__device__ __forceinline__ void glds16(const void* g, void* l) {
    __builtin_amdgcn_global_load_lds((const __attribute__((address_space(1))) void*)g,
                                     (__attribute__((address_space(3))) void*)l, 16, 0, 0);
}

// ---- cast x (fp32 -> bf16, layout-preserving) ----
__global__ __launch_bounds__(256) void cast_x_k(const float* __restrict__ in,
                                                unsigned short* __restrict__ out, int n) {
    int i = (blockIdx.x * 256 + threadIdx.x) * 4;
    if (i >= n) return;
    float4 v = *(const float4*)(in + i);
    ushort4 o;
    o.x = f2bf(v.x); o.y = f2bf(v.y); o.z = f2bf(v.z); o.w = f2bf(v.w);
    *(ushort4*)(out + i) = o;
}

// ---- cast + transpose weights via LDS tile (64x64): out[c][k] = in[k][c] ----
__global__ __launch_bounds__(256) void cast_wT_k(const float* __restrict__ w0, const float* __restrict__ w1,
                                                 const float* __restrict__ w2, const float* __restrict__ w3,
                                                 unsigned short* __restrict__ o0, unsigned short* __restrict__ o1,
                                                 unsigned short* __restrict__ o2, unsigned short* __restrict__ o3) {
    __shared__ unsigned short t[64][65];
    const float* in; unsigned short* out;
    switch (blockIdx.y) {
        case 0: in = w0; out = o0; break;
        case 1: in = w1; out = o1; break;
        case 2: in = w2; out = o2; break;
        default: in = w3; out = o3; break;
    }
    int kt = blockIdx.x / 12, ct = blockIdx.x % 12;
    int rr = threadIdx.x >> 4, cc = threadIdx.x & 15;
#pragma unroll
    for (int it = 0; it < 4; it++) {
        int row = kt * 64 + it * 16 + rr;
        int col = ct * 64 + cc * 4;
        float4 v = *(const float4*)(in + row * 768 + col);
        t[it * 16 + rr][cc * 4 + 0] = f2bf(v.x);
        t[it * 16 + rr][cc * 4 + 1] = f2bf(v.y);
        t[it * 16 + rr][cc * 4 + 2] = f2bf(v.z);
        t[it * 16 + rr][cc * 4 + 3] = f2bf(v.w);
    }
    __syncthreads();
#pragma unroll
    for (int it = 0; it < 4; it++) {
        int c_l = it * 16 + rr;
        int k_l = cc * 4;
        ushort4 o;
        o.x = t[k_l + 0][c_l];
        o.y = t[k_l + 1][c_l];
        o.z = t[k_l + 2][c_l];
        o.w = t[k_l + 3][c_l];
        *(ushort4*)(out + (ct * 64 + c_l) * 768 + kt * 64 + k_l) = o;
    }
}

// ---- fused QKV projection as one GEMM over N=2304; 3-buffer pipeline, counted vmcnt ----
__global__ __launch_bounds__(256) void qkv_gemm_k(
    const unsigned short* __restrict__ xb,
    const unsigned short* __restrict__ wqT, const unsigned short* __restrict__ wkT,
    const unsigned short* __restrict__ wvT,
    const float* __restrict__ bq, const float* __restrict__ bk, const float* __restrict__ bv,
    unsigned short* __restrict__ q, unsigned short* __restrict__ k, unsigned short* __restrict__ vT) {
    __shared__ unsigned short Abuf[3][128 * 32];
    __shared__ unsigned short Bbuf[3][128 * 32];

    int ctile = blockIdx.x;
    int mtile = blockIdx.y;
    int mat = ctile / 6;
    int col0 = (ctile % 6) * 128;
    const unsigned short* Bsrc = (mat == 0) ? wqT : ((mat == 1) ? wkT : wvT);
    const float* bias = (mat == 0) ? bq : ((mat == 1) ? bk : bv);

    int tid = threadIdx.x;
    int w = tid >> 6, l = tid & 63;
    int q16 = l & 15, g = l >> 4;
    int wr = w >> 1, wc = w & 1;

    int srow0 = tid >> 2;
    int ss = tid & 3;

    auto stage = [&](int tt, int buf) {
        int k0 = tt * 32;
#pragma unroll
        for (int i = 0; i < 2; ++i) {
            int row = srow0 + i * 64;
            int c16 = ss ^ ((row >> 1) & 3);
            glds16(xb + (mtile * 128 + row) * 768 + k0 + (c16 << 3),
                   (char*)&Abuf[buf][0] + i * 4096 + tid * 16);
            glds16(Bsrc + (col0 + row) * 768 + k0 + (c16 << 3),
                   (char*)&Bbuf[buf][0] + i * 4096 + tid * 16);
        }
    };

    v4f zero = {0.f, 0.f, 0.f, 0.f};
    v4f acc[4][4];
#pragma unroll
    for (int i = 0; i < 4; i++)
#pragma unroll
        for (int j = 0; j < 4; j++) acc[i][j] = zero;

    stage(0, 0);
    stage(1, 1);
    asm volatile("s_waitcnt vmcnt(4)" ::: "memory");
    __builtin_amdgcn_s_barrier();
    asm volatile("" ::: "memory");

    int rd = 0;
    for (int tt = 0; tt < 24; ++tt) {
        int st = rd + 2; if (st >= 3) st -= 3;
        if (tt + 2 < 24) stage(tt + 2, st);
        const char* Ab = (const char*)&Abuf[rd][0];
        const char* Bb = (const char*)&Bbuf[rd][0];
        v8s af[4], bf[4];
#pragma unroll
        for (int f = 0; f < 4; f++) {
            int arow = wr * 64 + f * 16 + q16;
            af[f] = *(const v8s*)(Ab + arow * 64 + ((g ^ ((arow >> 1) & 3)) << 4));
            int brow = wc * 64 + f * 16 + q16;
            bf[f] = *(const v8s*)(Bb + brow * 64 + ((g ^ ((brow >> 1) & 3)) << 4));
        }
#pragma unroll
        for (int i = 0; i < 4; i++)
#pragma unroll
            for (int j = 0; j < 4; j++)
                acc[i][j] = __builtin_amdgcn_mfma_f32_16x16x32_bf16(af[i], bf[j], acc[i][j], 0, 0, 0);
        asm volatile("s_waitcnt vmcnt(4)" ::: "memory");
        __builtin_amdgcn_s_barrier();
        asm volatile("" ::: "memory");
        rd = (rd + 1 == 3) ? 0 : rd + 1;
    }

    const float QSCL = 0.125f * 1.44269504088896340736f;
#pragma unroll
    for (int i = 0; i < 4; i++)
#pragma unroll
        for (int j = 0; j < 4; j++)
#pragma unroll
            for (int r = 0; r < 4; r++) {
                int gr = mtile * 128 + wr * 64 + i * 16 + 4 * g + r;
                int gcl = col0 + wc * 64 + j * 16 + q16;
                int b = gr / NN, n = gr % NN;
                int h = gcl / DH, d = gcl % DH;
                int bh = b * NH + h;
                float v = acc[i][j][r] + bias[gcl];
                if (mat == 0)      q[(bh * NN + n) * DH + d]  = f2bf(v * QSCL);
                else if (mat == 1) k[(bh * NN + n) * DH + d]  = f2bf(v);
                else               vT[(bh * DH + d) * NN + n] = f2bf(v);
            }
}

// ---- flash attention, 32x32 MFMA, 3-buffer K/V pipeline with counted vmcnt ----
#define MKFRAG(PC, BASE, FR) {                                                     \
    int a0 = cvtpk(PC[BASE + 0], PC[BASE + 1]), a1 = cvtpk(PC[BASE + 2], PC[BASE + 3]); \
    int b0 = cvtpk(PC[BASE + 4], PC[BASE + 5]), b1 = cvtpk(PC[BASE + 6], PC[BASE + 7]); \
    int t0 = hi ? a0 : b0, t1 = hi ? a1 : b1;                                      \
    int r0 = __shfl_xor(t0, 32), r1 = __shfl_xor(t1, 32);                          \
    union { int i[4]; v8s s; } u_;                                                 \
    u_.i[0] = hi ? r0 : a0; u_.i[1] = hi ? r1 : a1;                                \
    u_.i[2] = hi ? b0 : r0; u_.i[3] = hi ? b1 : r1;                                \
    FR = u_.s; }

__global__ __launch_bounds__(128) void attn_k(
    const unsigned short* __restrict__ q, const unsigned short* __restrict__ k,
    const unsigned short* __restrict__ vT, unsigned short* __restrict__ z) {
    __shared__ unsigned short Kb[3][4096];
    __shared__ unsigned short Vb[3][4096];

    int bh = blockIdx.x % 24;
    int qt = blockIdx.x / 24;
    int b = bh / NH, h = bh % NH;
    int tid = threadIdx.x;
    int w = tid >> 6, l = tid & 63;
    int hi = l >> 5, ln = l & 31, x7 = l & 7;
    const unsigned short* qp = q + (size_t)bh * NN * DH;
    const unsigned short* kp = k + (size_t)bh * NN * DH;
    const unsigned short* vp = vT + (size_t)bh * DH * NN;

    int qrow = qt * 64 + w * 32 + ln;
    v8s qf[4];
#pragma unroll
    for (int ks = 0; ks < 4; ++ks)
        qf[ks] = *(const v8s*)(qp + qrow * DH + 16 * ks + 8 * hi);

    auto stage = [&](int t, int buf) {
        int kv = t * 64;
#pragma unroll
        for (int i = 0; i < 4; ++i) {
            int slot = tid + 128 * i;
            int row = slot >> 3;
            int c16 = (slot & 7) ^ (row & 7);
            glds16(kp + (kv + row) * DH + (c16 << 3), (char*)&Kb[buf][0] + slot * 16);
            glds16(vp + row * NN + kv + (c16 << 3), (char*)&Vb[buf][0] + slot * 16);
        }
    };

    v16f o0, o1;
#pragma unroll
    for (int i = 0; i < 16; i++) { o0[i] = 0.f; o1[i] = 0.f; }
    float mrow = -INFINITY, lsum = 0.f;

    stage(0, 0);
    stage(1, 1);
    asm volatile("s_waitcnt vmcnt(8)" ::: "memory");
    __builtin_amdgcn_s_barrier();
    asm volatile("" ::: "memory");

    int rd = 0;
    for (int t = 0; t < NN / 64; ++t) {
        int st = rd + 2; if (st >= 3) st -= 3;
        if (t + 2 < NN / 64) stage(t + 2, st);
        const char* kbp = (const char*)&Kb[rd][0];
        const char* vbp = (const char*)&Vb[rd][0];

        v16f s0, s1;
#pragma unroll
        for (int i = 0; i < 16; i++) { s0[i] = 0.f; s1[i] = 0.f; }

        // ---- QK^T: S^T[64 kv][32 q] ----
        {
            v8s kf0[4], kf1[4];
#pragma unroll
            for (int ks = 0; ks < 4; ++ks) {
                kf0[ks] = *(const v8s*)(kbp + ln * 128 + (((2 * ks + hi) ^ x7) << 4));
                kf1[ks] = *(const v8s*)(kbp + (32 + ln) * 128 + (((2 * ks + hi) ^ x7) << 4));
            }
            __builtin_amdgcn_s_setprio(1);
#pragma unroll
            for (int ks = 0; ks < 4; ++ks) {
                s0 = __builtin_amdgcn_mfma_f32_32x32x16_bf16(kf0[ks], qf[ks], s0, 0, 0, 0);
                s1 = __builtin_amdgcn_mfma_f32_32x32x16_bf16(kf1[ks], qf[ks], s1, 0, 0, 0);
            }
            __builtin_amdgcn_s_setprio(0);
        }

        // ---- online softmax (defer-max, THR=8) ----
        float vmax = -1e30f;
#pragma unroll
        for (int i = 0; i < 16; i++) vmax = fmaxf(vmax, fmaxf(s0[i], s1[i]));
        vmax = fmaxf(vmax, __shfl_xor(vmax, 32));

        int need = !__all(vmax <= mrow + 8.f);
        if (need) {
            float mn = fmaxf(mrow, vmax);
            float sc = exp2f(mrow - mn);
#pragma unroll
            for (int r = 0; r < 16; ++r) {
                int addr = 4 * ((r & 3) + 8 * (r >> 2)) + (hi << 4);
                float scr = __uint_as_float(
                    __builtin_amdgcn_ds_bpermute(addr, __float_as_uint(sc)));
                o0[r] *= scr; o1[r] *= scr;
            }
            lsum *= sc;
            mrow = mn;
        }

        float rs = 0.f;
#pragma unroll
        for (int i = 0; i < 16; i++) {
            s0[i] = exp2f(s0[i] - mrow);
            s1[i] = exp2f(s1[i] - mrow);
            rs += s0[i] + s1[i];
        }
        rs += __shfl_xor(rs, 32);
        lsum += rs;

        // ---- P fragments (in-register redistribution) ----
        v8s pf[4];
        MKFRAG(s0, 0, pf[0]);
        MKFRAG(s0, 8, pf[1]);
        MKFRAG(s1, 0, pf[2]);
        MKFRAG(s1, 8, pf[3]);

        // ---- PV: O[32 q][64 d] ----
        {
            v8s vf0[4], vf1[4];
#pragma unroll
            for (int ks = 0; ks < 4; ++ks) {
                vf0[ks] = *(const v8s*)(vbp + ln * 128 + (((2 * ks + hi) ^ x7) << 4));
                vf1[ks] = *(const v8s*)(vbp + (32 + ln) * 128 + (((2 * ks + hi) ^ x7) << 4));
            }
            __builtin_amdgcn_s_setprio(1);
#pragma unroll
            for (int ks = 0; ks < 4; ++ks) {
                o0 = __builtin_amdgcn_mfma_f32_32x32x16_bf16(pf[ks], vf0[ks], o0, 0, 0, 0);
                o1 = __builtin_amdgcn_mfma_f32_32x32x16_bf16(pf[ks], vf1[ks], o1, 0, 0, 0);
            }
            __builtin_amdgcn_s_setprio(0);
        }
        asm volatile("s_waitcnt vmcnt(8)" ::: "memory");
        __builtin_amdgcn_s_barrier();
        asm volatile("" ::: "memory");
        rd = (rd + 1 == 3) ? 0 : rd + 1;
    }

    float inv = 1.f / lsum;
#pragma unroll
    for (int r = 0; r < 16; ++r) {
        int addr = 4 * ((r & 3) + 8 * (r >> 2)) + (hi << 4);
        float ir = __uint_as_float(__builtin_amdgcn_ds_bpermute(addr, __float_as_uint(inv)));
        int qg = qt * 64 + w * 32 + (r & 3) + 8 * (r >> 2) + 4 * hi;
        size_t base = ((size_t)(b * NN + qg)) * DM + h * DH;
        z[base + ln]      = f2bf(o0[r] * ir);
        z[base + 32 + ln] = f2bf(o1[r] * ir);
    }
}

// ---- output projection: z[4096,768] @ wo + bo -> fp32; 3-buffer pipeline ----
__global__ __launch_bounds__(256) void out_gemm_k(
    const unsigned short* __restrict__ zb, const unsigned short* __restrict__ woT,
    const float* __restrict__ bo, float* __restrict__ out) {
    __shared__ unsigned short Abuf[3][128 * 32];
    __shared__ unsigned short Bbuf[3][128 * 32];

    int ctile = blockIdx.x;
    int mtile = blockIdx.y;
    int col0 = ctile * 128;

    int tid = threadIdx.x;
    int w = tid >> 6, l = tid & 63;
    int q16 = l & 15, g = l >> 4;
    int wr = w >> 1, wc = w & 1;

    int srow0 = tid >> 2;
    int ss = tid & 3;

    auto stage = [&](int tt, int buf) {
        int k0 = tt * 32;
#pragma unroll
        for (int i = 0; i < 2; ++i) {
            int row = srow0 + i * 64;
            int c16 = ss ^ ((row >> 1) & 3);
            glds16(zb + (mtile * 128 + row) * 768 + k0 + (c16 << 3),
                   (char*)&Abuf[buf][0] + i * 4096 + tid * 16);
            glds16(woT + (col0 + row) * 768 + k0 + (c16 << 3),
                   (char*)&Bbuf[buf][0] + i * 4096 + tid * 16);
        }
    };

    v4f zero = {0.f, 0.f, 0.f, 0.f};
    v4f acc[4][4];
#pragma unroll
    for (int i = 0; i < 4; i++)
#pragma unroll
        for (int j = 0; j < 4; j++) acc[i][j] = zero;

    stage(0, 0);
    stage(1, 1);
    asm volatile("s_waitcnt vmcnt(4)" ::: "memory");
    __builtin_amdgcn_s_barrier();
    asm volatile("" ::: "memory");

    int rd = 0;
    for (int tt = 0; tt < 24; ++tt) {
        int st = rd + 2; if (st >= 3) st -= 3;
        if (tt + 2 < 24) stage(tt + 2, st);
        const char* Ab = (const char*)&Abuf[rd][0];
        const char* Bb = (const char*)&Bbuf[rd][0];
        v8s af[4], bf[4];
#pragma unroll
        for (int f = 0; f < 4; f++) {
            int arow = wr * 64 + f * 16 + q16;
            af[f] = *(const v8s*)(Ab + arow * 64 + ((g ^ ((arow >> 1) & 3)) << 4));
            int brow = wc * 64 + f * 16 + q16;
            bf[f] = *(const v8s*)(Bb + brow * 64 + ((g ^ ((brow >> 1) & 3)) << 4));
        }
#pragma unroll
        for (int i = 0; i < 4; i++)
#pragma unroll
            for (int j = 0; j < 4; j++)
                acc[i][j] = __builtin_amdgcn_mfma_f32_16x16x32_bf16(af[i], bf[j], acc[i][j], 0, 0, 0);
        asm volatile("s_waitcnt vmcnt(4)" ::: "memory");
        __builtin_amdgcn_s_barrier();
        asm volatile("" ::: "memory");
        rd = (rd + 1 == 3) ? 0 : rd + 1;
    }

#pragma unroll
    for (int i = 0; i < 4; i++)
#pragma unroll
        for (int j = 0; j < 4; j++)
#pragma unroll
            for (int r = 0; r < 4; r++) {
                int gr = mtile * 128 + wr * 64 + i * 16 + 4 * g + r;
                int gc = col0 + wc * 64 + j * 16 + q16;
                out[gr * 768 + gc] = acc[i][j][r] + bo[gc];
            }
}

extern "C" void kernel_launch(void* const* d_in, const int* in_sizes, int n_in,
                              void* d_out, int out_size, void* d_ws, size_t ws_size,
                              hipStream_t stream) {
    const float* x  = (const float*)d_in[0];
    const float* wq = (const float*)d_in[1];
    const float* bq = (const float*)d_in[2];
    const float* wk = (const float*)d_in[3];
    const float* bk = (const float*)d_in[4];
    const float* wv = (const float*)d_in[5];
    const float* bv = (const float*)d_in[6];
    const float* wo = (const float*)d_in[7];
    const float* bo = (const float*)d_in[8];
    float* out = (float*)d_out;

    const int NX = BB * NN * DM;
    const int NW = 768 * 768;

    unsigned short* wsp = (unsigned short*)d_ws;
    unsigned short* xb  = wsp;
    unsigned short* wqT = xb + NX;
    unsigned short* wkT = wqT + NW;
    unsigned short* wvT = wkT + NW;
    unsigned short* woT = wvT + NW;
    unsigned short* qb  = woT + NW;
    unsigned short* kb  = qb + NX;
    unsigned short* vTb = kb + NX;
    unsigned short* zb  = vTb + NX;

    cast_x_k<<<NX / (256 * 4), 256, 0, stream>>>(x, xb, NX);
    cast_wT_k<<<dim3(144, 4), 256, 0, stream>>>(wq, wk, wv, wo, wqT, wkT, wvT, woT);
    qkv_gemm_k<<<dim3(18, 32), 256, 0, stream>>>(xb, wqT, wkT, wvT, bq, bk, bv, qb, kb, vTb);
    attn_k<<<BB * NH * (NN / 64), 128, 0, stream>>>(qb, kb, vTb, zb);
    out_gemm_k<<<dim3(6, 32), 256, 0, stream>>>(zb, woT, bo, out);
}

// Round 7
// 144.463 us; speedup vs baseline: 1.0459x; 1.0220x over previous
//
#include <hip/hip_runtime.h>
#include <hip/hip_bf16.h>
#include <math.h>

#define NH 12
#define DH 64
#define BB 2
#define NN 2048
#define DM 768

typedef short v8s __attribute__((ext_vector_type(8)));
typedef float v4f __attribute__((ext_vector_type(4)));
typedef float v16f __attribute__((ext_vector_type(16)));

__device__ __forceinline__ unsigned short f2bf(float f) {
    union { float f; unsigned u; } x; x.f = f;
    unsigned r = x.u + 0x7fffu + ((x.u >> 16) & 1u);
    return (unsigned short)(r >> 16);
}

__device__ __forceinline__ int cvtpk(float lo, float hi2) {
    int r;
    asm("v_cvt_pk_bf16_f32 %0, %1, %2" : "=v"(r) : "v"(lo), "v"(hi2));
    return r;
}

__device__ __forceinline__ void glds16(const void* g, void* l) {
    __builtin_amdgcn_global_load_lds((const __attribute__((address_space(1))) void*)g,
                                     (__attribute__((address_space(3))) void*)l, 16, 0, 0);
}

// ---- cast x (fp32 -> bf16, layout-preserving) ----
__global__ __launch_bounds__(256) void cast_x_k(const float* __restrict__ in,
                                                unsigned short* __restrict__ out, int n) {
    int i = (blockIdx.x * 256 + threadIdx.x) * 4;
    if (i >= n) return;
    float4 v = *(const float4*)(in + i);
    ushort4 o;
    o.x = f2bf(v.x); o.y = f2bf(v.y); o.z = f2bf(v.z); o.w = f2bf(v.w);
    *(ushort4*)(out + i) = o;
}

// ---- cast + transpose weights via LDS tile (64x64): out[c][k] = in[k][c] ----
__global__ __launch_bounds__(256) void cast_wT_k(const float* __restrict__ w0, const float* __restrict__ w1,
                                                 const float* __restrict__ w2, const float* __restrict__ w3,
                                                 unsigned short* __restrict__ o0, unsigned short* __restrict__ o1,
                                                 unsigned short* __restrict__ o2, unsigned short* __restrict__ o3) {
    __shared__ unsigned short t[64][65];
    const float* in; unsigned short* out;
    switch (blockIdx.y) {
        case 0: in = w0; out = o0; break;
        case 1: in = w1; out = o1; break;
        case 2: in = w2; out = o2; break;
        default: in = w3; out = o3; break;
    }
    int kt = blockIdx.x / 12, ct = blockIdx.x % 12;
    int rr = threadIdx.x >> 4, cc = threadIdx.x & 15;
#pragma unroll
    for (int it = 0; it < 4; it++) {
        int row = kt * 64 + it * 16 + rr;
        int col = ct * 64 + cc * 4;
        float4 v = *(const float4*)(in + row * 768 + col);
        t[it * 16 + rr][cc * 4 + 0] = f2bf(v.x);
        t[it * 16 + rr][cc * 4 + 1] = f2bf(v.y);
        t[it * 16 + rr][cc * 4 + 2] = f2bf(v.z);
        t[it * 16 + rr][cc * 4 + 3] = f2bf(v.w);
    }
    __syncthreads();
#pragma unroll
    for (int it = 0; it < 4; it++) {
        int c_l = it * 16 + rr;
        int k_l = cc * 4;
        ushort4 o;
        o.x = t[k_l + 0][c_l];
        o.y = t[k_l + 1][c_l];
        o.z = t[k_l + 2][c_l];
        o.w = t[k_l + 3][c_l];
        *(ushort4*)(out + (ct * 64 + c_l) * 768 + kt * 64 + k_l) = o;
    }
}

// ---- fused QKV projection as one GEMM over N=2304; 3-buffer pipeline, counted vmcnt ----
__global__ __launch_bounds__(256) void qkv_gemm_k(
    const unsigned short* __restrict__ xb,
    const unsigned short* __restrict__ wqT, const unsigned short* __restrict__ wkT,
    const unsigned short* __restrict__ wvT,
    const float* __restrict__ bq, const float* __restrict__ bk, const float* __restrict__ bv,
    unsigned short* __restrict__ q, unsigned short* __restrict__ k, unsigned short* __restrict__ vT) {
    __shared__ unsigned short Abuf[3][128 * 32];
    __shared__ unsigned short Bbuf[3][128 * 32];

    int ctile = blockIdx.x;
    int mtile = blockIdx.y;
    int mat = ctile / 6;
    int col0 = (ctile % 6) * 128;
    const unsigned short* Bsrc = (mat == 0) ? wqT : ((mat == 1) ? wkT : wvT);
    const float* bias = (mat == 0) ? bq : ((mat == 1) ? bk : bv);

    int tid = threadIdx.x;
    int w = tid >> 6, l = tid & 63;
    int q16 = l & 15, g = l >> 4;
    int wr = w >> 1, wc = w & 1;

    int srow0 = tid >> 2;
    int ss = tid & 3;

    auto stage = [&](int tt, int buf) {
        int k0 = tt * 32;
#pragma unroll
        for (int i = 0; i < 2; ++i) {
            int row = srow0 + i * 64;
            int c16 = ss ^ ((row >> 1) & 3);
            glds16(xb + (mtile * 128 + row) * 768 + k0 + (c16 << 3),
                   (char*)&Abuf[buf][0] + i * 4096 + tid * 16);
            glds16(Bsrc + (col0 + row) * 768 + k0 + (c16 << 3),
                   (char*)&Bbuf[buf][0] + i * 4096 + tid * 16);
        }
    };

    v4f zero = {0.f, 0.f, 0.f, 0.f};
    v4f acc[4][4];
#pragma unroll
    for (int i = 0; i < 4; i++)
#pragma unroll
        for (int j = 0; j < 4; j++) acc[i][j] = zero;

    stage(0, 0);
    stage(1, 1);
    asm volatile("s_waitcnt vmcnt(4)" ::: "memory");
    __builtin_amdgcn_s_barrier();
    asm volatile("" ::: "memory");

    int rd = 0;
    for (int tt = 0; tt < 24; ++tt) {
        int st = rd + 2; if (st >= 3) st -= 3;
        if (tt + 2 < 24) stage(tt + 2, st);
        const char* Ab = (const char*)&Abuf[rd][0];
        const char* Bb = (const char*)&Bbuf[rd][0];
        v8s af[4], bf[4];
#pragma unroll
        for (int f = 0; f < 4; f++) {
            int arow = wr * 64 + f * 16 + q16;
            af[f] = *(const v8s*)(Ab + arow * 64 + ((g ^ ((arow >> 1) & 3)) << 4));
            int brow = wc * 64 + f * 16 + q16;
            bf[f] = *(const v8s*)(Bb + brow * 64 + ((g ^ ((brow >> 1) & 3)) << 4));
        }
#pragma unroll
        for (int i = 0; i < 4; i++)
#pragma unroll
            for (int j = 0; j < 4; j++)
                acc[i][j] = __builtin_amdgcn_mfma_f32_16x16x32_bf16(af[i], bf[j], acc[i][j], 0, 0, 0);
        asm volatile("s_waitcnt vmcnt(4)" ::: "memory");
        __builtin_amdgcn_s_barrier();
        asm volatile("" ::: "memory");
        rd = (rd + 1 == 3) ? 0 : rd + 1;
    }

    const float QSCL = 0.125f * 1.44269504088896340736f;
#pragma unroll
    for (int i = 0; i < 4; i++)
#pragma unroll
        for (int j = 0; j < 4; j++)
#pragma unroll
            for (int r = 0; r < 4; r++) {
                int gr = mtile * 128 + wr * 64 + i * 16 + 4 * g + r;
                int gcl = col0 + wc * 64 + j * 16 + q16;
                int b = gr / NN, n = gr % NN;
                int h = gcl / DH, d = gcl % DH;
                int bh = b * NH + h;
                float v = acc[i][j][r] + bias[gcl];
                if (mat == 0)      q[(bh * NN + n) * DH + d]  = f2bf(v * QSCL);
                else if (mat == 1) k[(bh * NN + n) * DH + d]  = f2bf(v);
                else               vT[(bh * DH + d) * NN + n] = f2bf(v);
            }
}

// ---- flash attention: 4 waves = 2 q-strips x 2 kv-halves; 32x32 MFMA; kv tile 32 ----
// Wave (strip, half): q rows [qt*64+strip*32, +32), kv range [half*1024, +1024).
// End: half-1 publishes (o,m,l) via LDS; half-0 merges (online-softmax combine) and writes z.
#define MKFRAG(PC, BASE, FR) {                                                     \
    int a0 = cvtpk(PC[BASE + 0], PC[BASE + 1]), a1 = cvtpk(PC[BASE + 2], PC[BASE + 3]); \
    int b0 = cvtpk(PC[BASE + 4], PC[BASE + 5]), b1 = cvtpk(PC[BASE + 6], PC[BASE + 7]); \
    int t0 = hi ? a0 : b0, t1 = hi ? a1 : b1;                                      \
    int r0 = __shfl_xor(t0, 32), r1 = __shfl_xor(t1, 32);                          \
    union { int i[4]; v8s s; } u_;                                                 \
    u_.i[0] = hi ? r0 : a0; u_.i[1] = hi ? r1 : a1;                                \
    u_.i[2] = hi ? b0 : r0; u_.i[3] = hi ? b1 : r1;                                \
    FR = u_.s; }

__global__ __launch_bounds__(256) void attn_k(
    const unsigned short* __restrict__ q, const unsigned short* __restrict__ k,
    const unsigned short* __restrict__ vT, unsigned short* __restrict__ z) {
    // [0,16384): K tiles (2 halves x 2 bufs x 4KB); [16384,32768): V tiles.
    // After the loop the first 16KB is reused as the f32 partial-o exchange area.
    __shared__ __align__(16) char smem[32768];
    __shared__ float pml[2][2][32];

    int bh = blockIdx.x % 24;
    int qt = blockIdx.x / 24;
    int b = bh / NH, h = bh % NH;
    int tid = threadIdx.x;
    int w = tid >> 6, l = tid & 63;
    int hi = l >> 5, ln = l & 31;
    int strip = w & 1, half = w >> 1;
    int idx128 = strip * 64 + l;              // thread index within this half's 128 threads

    const unsigned short* qp = q + (size_t)bh * NN * DH;
    const unsigned short* kp = k + (size_t)bh * NN * DH;
    const unsigned short* vp = vT + (size_t)bh * DH * NN;

    int qrow = qt * 64 + strip * 32 + ln;
    v8s qf[4];
#pragma unroll
    for (int ks = 0; ks < 4; ++ks)
        qf[ks] = *(const v8s*)(qp + qrow * DH + 16 * ks + 8 * hi);

    char* Kh = smem + half * 8192;            // 2 bufs x 4KB (K tile 32kv x 64d, 128B rows)
    char* Vh = smem + 16384 + half * 8192;    // 2 bufs x 4KB (V^T tile 64d x 32kv, 64B rows)

    auto stage = [&](int t, int buf) {
        int kv0 = half * (NN / 2) + t * 32;
#pragma unroll
        for (int i = 0; i < 2; ++i) {
            int slot = idx128 + 128 * i;      // 0..255
            int kr = slot >> 3, kss = slot & 7;
            glds16(kp + (kv0 + kr) * DH + ((kss ^ (kr & 7)) << 3), Kh + buf * 4096 + slot * 16);
            int vr = slot >> 2, vs = slot & 3;
            glds16(vp + (size_t)vr * NN + kv0 + ((vs ^ (vr & 3)) << 3), Vh + buf * 4096 + slot * 16);
        }
    };

    v16f o0, o1;
#pragma unroll
    for (int i = 0; i < 16; i++) { o0[i] = 0.f; o1[i] = 0.f; }
    float mrow = -INFINITY, lsum = 0.f;

    stage(0, 0);
    asm volatile("s_waitcnt vmcnt(0)" ::: "memory");
    __builtin_amdgcn_s_barrier();
    asm volatile("" ::: "memory");

    int buf = 0;
    for (int t = 0; t < 32; ++t) {
        if (t + 1 < 32) stage(t + 1, buf ^ 1);
        const char* kb = Kh + buf * 4096;
        const char* vb = Vh + buf * 4096;

        v16f s;
#pragma unroll
        for (int i = 0; i < 16; i++) s[i] = 0.f;

        // ---- QK^T: S^T[32 kv][32 q] ----
        {
            v8s kf[4];
#pragma unroll
            for (int ks = 0; ks < 4; ++ks)
                kf[ks] = *(const v8s*)(kb + ln * 128 + (((2 * ks + hi) ^ (ln & 7)) << 4));
            __builtin_amdgcn_s_setprio(1);
#pragma unroll
            for (int ks = 0; ks < 4; ++ks)
                s = __builtin_amdgcn_mfma_f32_32x32x16_bf16(kf[ks], qf[ks], s, 0, 0, 0);
            __builtin_amdgcn_s_setprio(0);
        }

        // ---- online softmax (defer-max, THR=8) ----
        float vmax = -1e30f;
#pragma unroll
        for (int i = 0; i < 16; i++) vmax = fmaxf(vmax, s[i]);
        vmax = fmaxf(vmax, __shfl_xor(vmax, 32));

        if (!__all(vmax <= mrow + 8.f)) {
            float mn = fmaxf(mrow, vmax);
            float sc = exp2f(mrow - mn);
#pragma unroll
            for (int r = 0; r < 16; ++r) {
                int addr = 4 * ((r & 3) + 8 * (r >> 2)) + (hi << 4);
                float scr = __uint_as_float(
                    __builtin_amdgcn_ds_bpermute(addr, __float_as_uint(sc)));
                o0[r] *= scr; o1[r] *= scr;
            }
            lsum *= sc;
            mrow = mn;
        }

        float rs = 0.f;
#pragma unroll
        for (int i = 0; i < 16; i++) {
            s[i] = exp2f(s[i] - mrow);
            rs += s[i];
        }
        rs += __shfl_xor(rs, 32);
        lsum += rs;

        // ---- P fragments (in-register redistribution) ----
        v8s pf[2];
        MKFRAG(s, 0, pf[0]);
        MKFRAG(s, 8, pf[1]);

        // ---- PV: O[32 q][64 d] ----
        {
            v8s vf0[2], vf1[2];
#pragma unroll
            for (int ks = 0; ks < 2; ++ks) {
                vf0[ks] = *(const v8s*)(vb + ln * 64 + (((2 * ks + hi) ^ (ln & 3)) << 4));
                vf1[ks] = *(const v8s*)(vb + (32 + ln) * 64 + (((2 * ks + hi) ^ (ln & 3)) << 4));
            }
            __builtin_amdgcn_s_setprio(1);
#pragma unroll
            for (int ks = 0; ks < 2; ++ks) {
                o0 = __builtin_amdgcn_mfma_f32_32x32x16_bf16(pf[ks], vf0[ks], o0, 0, 0, 0);
                o1 = __builtin_amdgcn_mfma_f32_32x32x16_bf16(pf[ks], vf1[ks], o1, 0, 0, 0);
            }
            __builtin_amdgcn_s_setprio(0);
        }
        asm volatile("s_waitcnt vmcnt(0)" ::: "memory");
        __builtin_amdgcn_s_barrier();
        asm volatile("" ::: "memory");
        buf ^= 1;
    }

    // ---- cross-half combine ----
    if (half == 1) {
        float* po = (float*)smem;
#pragma unroll
        for (int r = 0; r < 16; ++r) {
            po[((strip * 2 + 0) * 16 + r) * 64 + l] = o0[r];
            po[((strip * 2 + 1) * 16 + r) * 64 + l] = o1[r];
        }
        pml[strip][0][ln] = mrow;
        pml[strip][1][ln] = lsum;
    }
    __syncthreads();
    if (half == 0) {
        const float* po = (const float*)smem;
        float m1 = pml[strip][0][ln], l1 = pml[strip][1][ln];
        float ms = fmaxf(mrow, m1);
        float a0 = exp2f(mrow - ms), a1 = exp2f(m1 - ms);
        float inv = 1.f / (lsum * a0 + l1 * a1);
        float ca = a0 * inv, cb = a1 * inv;
#pragma unroll
        for (int r = 0; r < 16; ++r) {
            int addr = 4 * ((r & 3) + 8 * (r >> 2)) + (hi << 4);
            float car = __uint_as_float(__builtin_amdgcn_ds_bpermute(addr, __float_as_uint(ca)));
            float cbr = __uint_as_float(__builtin_amdgcn_ds_bpermute(addr, __float_as_uint(cb)));
            float z0 = o0[r] * car + po[((strip * 2 + 0) * 16 + r) * 64 + l] * cbr;
            float z1 = o1[r] * car + po[((strip * 2 + 1) * 16 + r) * 64 + l] * cbr;
            int qg = qt * 64 + strip * 32 + (r & 3) + 8 * (r >> 2) + 4 * hi;
            size_t base = ((size_t)(b * NN + qg)) * DM + h * DH;
            z[base + ln]      = f2bf(z0);
            z[base + 32 + ln] = f2bf(z1);
        }
    }
}

// ---- output projection: z[4096,768] @ wo + bo -> fp32; 3-buffer pipeline ----
__global__ __launch_bounds__(256) void out_gemm_k(
    const unsigned short* __restrict__ zb, const unsigned short* __restrict__ woT,
    const float* __restrict__ bo, float* __restrict__ out) {
    __shared__ unsigned short Abuf[3][128 * 32];
    __shared__ unsigned short Bbuf[3][128 * 32];

    int ctile = blockIdx.x;
    int mtile = blockIdx.y;
    int col0 = ctile * 128;

    int tid = threadIdx.x;
    int w = tid >> 6, l = tid & 63;
    int q16 = l & 15, g = l >> 4;
    int wr = w >> 1, wc = w & 1;

    int srow0 = tid >> 2;
    int ss = tid & 3;

    auto stage = [&](int tt, int buf) {
        int k0 = tt * 32;
#pragma unroll
        for (int i = 0; i < 2; ++i) {
            int row = srow0 + i * 64;
            int c16 = ss ^ ((row >> 1) & 3);
            glds16(zb + (mtile * 128 + row) * 768 + k0 + (c16 << 3),
                   (char*)&Abuf[buf][0] + i * 4096 + tid * 16);
            glds16(woT + (col0 + row) * 768 + k0 + (c16 << 3),
                   (char*)&Bbuf[buf][0] + i * 4096 + tid * 16);
        }
    };

    v4f zero = {0.f, 0.f, 0.f, 0.f};
    v4f acc[4][4];
#pragma unroll
    for (int i = 0; i < 4; i++)
#pragma unroll
        for (int j = 0; j < 4; j++) acc[i][j] = zero;

    stage(0, 0);
    stage(1, 1);
    asm volatile("s_waitcnt vmcnt(4)" ::: "memory");
    __builtin_amdgcn_s_barrier();
    asm volatile("" ::: "memory");

    int rd = 0;
    for (int tt = 0; tt < 24; ++tt) {
        int st = rd + 2; if (st >= 3) st -= 3;
        if (tt + 2 < 24) stage(tt + 2, st);
        const char* Ab = (const char*)&Abuf[rd][0];
        const char* Bb = (const char*)&Bbuf[rd][0];
        v8s af[4], bf[4];
#pragma unroll
        for (int f = 0; f < 4; f++) {
            int arow = wr * 64 + f * 16 + q16;
            af[f] = *(const v8s*)(Ab + arow * 64 + ((g ^ ((arow >> 1) & 3)) << 4));
            int brow = wc * 64 + f * 16 + q16;
            bf[f] = *(const v8s*)(Bb + brow * 64 + ((g ^ ((brow >> 1) & 3)) << 4));
        }
#pragma unroll
        for (int i = 0; i < 4; i++)
#pragma unroll
            for (int j = 0; j < 4; j++)
                acc[i][j] = __builtin_amdgcn_mfma_f32_16x16x32_bf16(af[i], bf[j], acc[i][j], 0, 0, 0);
        asm volatile("s_waitcnt vmcnt(4)" ::: "memory");
        __builtin_amdgcn_s_barrier();
        asm volatile("" ::: "memory");
        rd = (rd + 1 == 3) ? 0 : rd + 1;
    }

#pragma unroll
    for (int i = 0; i < 4; i++)
#pragma unroll
        for (int j = 0; j < 4; j++)
#pragma unroll
            for (int r = 0; r < 4; r++) {
                int gr = mtile * 128 + wr * 64 + i * 16 + 4 * g + r;
                int gc = col0 + wc * 64 + j * 16 + q16;
                out[gr * 768 + gc] = acc[i][j][r] + bo[gc];
            }
}

extern "C" void kernel_launch(void* const* d_in, const int* in_sizes, int n_in,
                              void* d_out, int out_size, void* d_ws, size_t ws_size,
                              hipStream_t stream) {
    const float* x  = (const float*)d_in[0];
    const float* wq = (const float*)d_in[1];
    const float* bq = (const float*)d_in[2];
    const float* wk = (const float*)d_in[3];
    const float* bk = (const float*)d_in[4];
    const float* wv = (const float*)d_in[5];
    const float* bv = (const float*)d_in[6];
    const float* wo = (const float*)d_in[7];
    const float* bo = (const float*)d_in[8];
    float* out = (float*)d_out;

    const int NX = BB * NN * DM;
    const int NW = 768 * 768;

    unsigned short* wsp = (unsigned short*)d_ws;
    unsigned short* xb  = wsp;
    unsigned short* wqT = xb + NX;
    unsigned short* wkT = wqT + NW;
    unsigned short* wvT = wkT + NW;
    unsigned short* woT = wvT + NW;
    unsigned short* qb  = woT + NW;
    unsigned short* kb  = qb + NX;
    unsigned short* vTb = kb + NX;
    unsigned short* zb  = vTb + NX;

    cast_x_k<<<NX / (256 * 4), 256, 0, stream>>>(x, xb, NX);
    cast_wT_k<<<dim3(144, 4), 256, 0, stream>>>(wq, wk, wv, wo, wqT, wkT, wvT, woT);
    qkv_gemm_k<<<dim3(18, 32), 256, 0, stream>>>(xb, wqT, wkT, wvT, bq, bk, bv, qb, kb, vTb);
    attn_k<<<BB * NH * (NN / 64), 256, 0, stream>>>(qb, kb, vTb, zb);
    out_gemm_k<<<dim3(6, 32), 256, 0, stream>>>(zb, woT, bo, out);
}